// Round 11
// baseline (162.734 us; speedup 1.0000x reference)
//
#include <hip/hip_runtime.h>

typedef _Float16 f16x8 __attribute__((ext_vector_type(8)));
typedef _Float16 f16x2 __attribute__((ext_vector_type(2)));
typedef float    f32x4 __attribute__((ext_vector_type(4)));

#define MFMA(a, b, c) __builtin_amdgcn_mfma_f32_16x16x32_f16((a), (b), (c), 0, 0, 0)

__device__ inline f16x8 zero8() {
    f16x8 z;
#pragma unroll
    for (int i = 0; i < 8; ++i) z[i] = (_Float16)0.0f;
    return z;
}

// R10 + paired staging columns. Staging col space relabeled c'' = 2*l15 + h so
// the (h=0,h=1) channel pair is ADJACENT -> one f16x2 b32 store per (tile,r)
// instead of two b16 stores (staging DS ops 256->128/tile). Consumer b128
// A-frag reads unchanged; the induced slot permutation
//   k_slot(quad,j) <-> channel ks*32 + (j&1)*16 + quad*4 + (j>>1)
// is absorbed into the W2f / W3c pre-packs (verified-algebra class, derived
// from the R3 hardware-proven canonical maps).
// BAN: __launch_bounds__ min-waves >= 2 (5/5 such builds miscompiled).
// Occupancy rule (R5-R10): total VGPR+AGPR <= 256 -> 8 waves/CU; acc2 = 128
// AGPR pins us there, so keep arch VGPR ~124.
__global__ __launch_bounds__(256, 1)
void DeformationCorrector_78967268704761_kernel(
        const float* __restrict__ F,
        const float* __restrict__ W1, const float* __restrict__ b1,
        const float* __restrict__ W2, const float* __restrict__ b2,
        const float* __restrict__ W3, const float* __restrict__ b3,
        float* __restrict__ out, int N)
{
    __shared__ __align__(16) _Float16 W2f[8][4][64][8];   // 32 KB layer2 b-frags (paired-col perm)
    __shared__ __align__(16) _Float16 W1f[8][16][8];      // 2 KB  layer1 B-frags, lanes<16 (k<8)
    __shared__ __align__(16) _Float16 W3c[4][16][8];      // 1 KB  layer3 B-frags (paired-col perm)
    __shared__ __align__(16) _Float16 invL[256][8];       // 4 KB  per-point invariants
    __shared__ __align__(16) _Float16 scratch[4][64][40]; // 20 KB per-wave h slice (also xls alias)

    const int tid  = threadIdx.x;
    const int lane = tid & 63;
    const int w    = tid >> 6;
    const int l15  = tid & 15;
    const int quad = (tid >> 4) & 3;

    // ---------------- weight pre-pack (once per block) ----------------
    for (int m = tid; m < 128 * 128; m += 256) {          // W2[k][n] -> paired-col frag
        int k = m >> 7, n = m & 127;
        int ks = k >> 5, r5 = k & 31;
        int c2 = ((r5 & 15) << 1) | ((r5 >> 4) & 1);      // c'' = 2*l15p + h
        W2f[n >> 4][ks][(c2 >> 3) * 16 + (n & 15)][c2 & 7] = (_Float16)W2[m];
    }
    for (int f = tid; f < 1024; f += 256) {               // W1 b-frags: B[k=j][n], k=7 -> b1
        int nt = f >> 7, n15 = (f >> 3) & 15, j = f & 7;
        W1f[nt][n15][j] = (_Float16)((j < 7) ? W1[j * 128 + nt * 16 + n15]
                                             : b1[nt * 16 + n15]);
    }
    for (int f = tid; f < 512; f += 256) {                // W3 b-frags (paired-col perm)
        int s = f >> 7, idx = (f >> 3) & 15, j = f & 7;
        int q = idx >> 2, n3 = idx & 3;
        int ch = s * 32 + (j & 1) * 16 + q * 4 + (j >> 1);
        W3c[s][idx][j] = (_Float16)W3[ch * 4 + n3];
    }
    float b2r[8];
#pragma unroll
    for (int nt = 0; nt < 8; ++nt) b2r[nt] = b2[nt * 16 + l15];
    const float b3v = (l15 < 4) ? b3[l15] : 0.f;
    __syncthreads();   // only barrier; all main-loop LDS traffic is wave-private

    const int ntiles = (N + 255) >> 8;
    const int stride = (int)gridDim.x;

    // prime the F prefetch for the first tile
    float a, b, c, d;
    {
        const int p0 = blockIdx.x * 256 + tid;
        if (blockIdx.x < ntiles && p0 < N) {
            const float4 f4 = *(const float4*)(F + 4ll * p0);
            a = f4.x; b = f4.y; c = f4.z; d = f4.w;
        } else { a = 1.f; b = 0.f; c = 0.f; d = 1.f; }
    }

    for (int tile = blockIdx.x; tile < ntiles; tile += stride) {
        // ---------------- prefetch next tile's F (overlaps whole body) ----------------
        float na = 1.f, nb = 0.f, nc = 0.f, nd = 1.f;
        {
            const int pn = (tile + stride) * 256 + tid;
            if (tile + stride < ntiles && pn < N) {
                const float4 f4 = *(const float4*)(F + 4ll * pn);
                na = f4.x; nb = f4.y; nc = f4.z; nd = f4.w;
            }
        }
        const int p = tile * 256 + tid;

        // ---------------- invariants + polar (fp32, verified) ----------------
        const float x1 = a + d, y1 = c - b, x2 = a - d, y2 = c + b;
        const float h1v = sqrtf(x1 * x1 + y1 * y1);
        const float h2v = sqrtf(x2 * x2 + y2 * y2);
        const float s1 = 0.5f * (h1v + h2v), s2 = 0.5f * (h1v - h2v);
        const float ir = 1.0f / h1v;
        const float Rc = x1 * ir, Rs = y1 * ir;
        f16x8 iv;
        iv[0] = (_Float16)(s1 - 1.f);
        iv[1] = (_Float16)(s2 - 1.f);
        iv[2] = (_Float16)(a * a + c * c - 1.f);
        const float i3 = a * b + c * d;
        iv[3] = (_Float16)i3;
        iv[4] = (_Float16)i3;
        iv[5] = (_Float16)(b * b + d * d - 1.f);
        iv[6] = (_Float16)(a * d - b * c - 1.f);
        iv[7] = (_Float16)1.0f;
        *(f16x8*)(&invL[tid][0]) = iv;

        // inv A-frags: A[m=l15][k=quad*8+j], nonzero only quad==0 (k<8)
        f16x8 binv[4];
#pragma unroll
        for (int mt = 0; mt < 4; ++mt)
            binv[mt] = (quad == 0) ? *(const f16x8*)(&invL[w * 64 + mt * 16 + l15][0])
                                   : zero8();

        // ---------------- layers 1+2 per 32-channel chunk ----------------
        f32x4 acc2[8][4];   // [nt2][mt2]
#pragma unroll
        for (int nt2 = 0; nt2 < 8; ++nt2)
#pragma unroll
            for (int mt2 = 0; mt2 < 4; ++mt2) acc2[nt2][mt2] = (f32x4){0.f, 0.f, 0.f, 0.f};

        for (int ks = 0; ks < 4; ++ks) {
            // layer-1 MFMA pair (h=0,1) -> packed f16x2 staging store
            const f16x8 bw1a = (lane < 16) ? *(const f16x8*)(&W1f[2 * ks + 0][l15][0])
                                           : zero8();
            const f16x8 bw1b = (lane < 16) ? *(const f16x8*)(&W1f[2 * ks + 1][l15][0])
                                           : zero8();
#pragma unroll
            for (int mt = 0; mt < 4; ++mt) {
                f32x4 cz = {0.f, 0.f, 0.f, 0.f};
                const f32x4 c0 = MFMA(binv[mt], bw1a, cz);
                const f32x4 c1 = MFMA(binv[mt], bw1b, cz);
#pragma unroll
                for (int r = 0; r < 4; ++r) {
                    f16x2 pw;
                    pw[0] = (_Float16)fmaxf(c0[r], 0.f);
                    pw[1] = (_Float16)fmaxf(c1[r], 0.f);
                    *(f16x2*)(&scratch[w][mt * 16 + quad * 4 + r][2 * l15]) = pw;
                }
            }
            // layer-2: a-frags from slice (cols = c'' slots) + paired-perm W2 b-frags
            f16x8 af[4];
#pragma unroll
            for (int mt2 = 0; mt2 < 4; ++mt2)
                af[mt2] = *(const f16x8*)(&scratch[w][mt2 * 16 + l15][quad * 8]);
#pragma unroll
            for (int nt2 = 0; nt2 < 8; ++nt2) {
                const f16x8 bf = *(const f16x8*)(&W2f[nt2][ks][lane][0]);
#pragma unroll
                for (int mt2 = 0; mt2 < 4; ++mt2)
                    acc2[nt2][mt2] = MFMA(af[mt2], bf, acc2[nt2][mt2]);
            }
        }

        // ---------------- layer 3 per 32-channel chunk (MFMA) ----------------
        f32x4 acc3[4];
#pragma unroll
        for (int mt2 = 0; mt2 < 4; ++mt2) acc3[mt2] = (f32x4){0.f, 0.f, 0.f, 0.f};

#pragma unroll
        for (int s = 0; s < 4; ++s) {
            const float bb0 = b2r[2 * s], bb1 = b2r[2 * s + 1];
#pragma unroll
            for (int mt2 = 0; mt2 < 4; ++mt2)
#pragma unroll
                for (int r = 0; r < 4; ++r) {
                    f16x2 pw;
                    pw[0] = (_Float16)fmaxf(acc2[2 * s + 0][mt2][r] + bb0, 0.f);
                    pw[1] = (_Float16)fmaxf(acc2[2 * s + 1][mt2][r] + bb1, 0.f);
                    *(f16x2*)(&scratch[w][mt2 * 16 + quad * 4 + r][2 * l15]) = pw;
                }
            const f16x8 bw3 = (l15 < 4) ? *(const f16x8*)(&W3c[s][quad * 4 + l15][0])
                                        : zero8();
#pragma unroll
            for (int mt2 = 0; mt2 < 4; ++mt2) {
                const f16x8 ah = *(const f16x8*)(&scratch[w][mt2 * 16 + l15][quad * 8]);
                acc3[mt2] = MFMA(ah, bw3, acc3[mt2]);
            }
        }

        // ---------------- epilogue: x via scratch alias -> R@x + F ----------------
        float* xf = (float*)(&scratch[w][0][0]);   // 1 KB of the 5 KB wave slice
#pragma unroll
        for (int mt2 = 0; mt2 < 4; ++mt2)
#pragma unroll
            for (int r = 0; r < 4; ++r)
                if (l15 < 4)
                    xf[(mt2 * 16 + quad * 4 + r) * 4 + l15] = acc3[mt2][r] + b3v;

        const float4 xv = *(const float4*)(&xf[lane * 4]);
        const float xm  = 0.5f * (xv.y + xv.z);
        const float d00 = Rc * xv.x - Rs * xm;
        const float d01 = Rc * xm   - Rs * xv.w;
        const float d10 = Rs * xv.x + Rc * xm;
        const float d11 = Rs * xm   + Rc * xv.w;
        if (p < N) {
            float4 o;
            o.x = a + d00; o.y = b + d01; o.z = c + d10; o.w = d + d11;
            *(float4*)(out + 4ll * p) = o;
        }

        // rotate prefetched F into place for the next tile
        a = na; b = nb; c = nc; d = nd;
    }
}

extern "C" void kernel_launch(void* const* d_in, const int* in_sizes, int n_in,
                              void* d_out, int out_size, void* d_ws, size_t ws_size,
                              hipStream_t stream) {
    const float* F  = (const float*)d_in[0];
    const float* W1 = (const float*)d_in[1];
    const float* b1 = (const float*)d_in[2];
    const float* W2 = (const float*)d_in[3];
    const float* b2 = (const float*)d_in[4];
    const float* W3 = (const float*)d_in[5];
    const float* b3 = (const float*)d_in[6];
    float* out = (float*)d_out;
    const int N = in_sizes[0] / 4;
    const int ntiles = (N + 255) / 256;
    const int grid = ntiles < 512 ? ntiles : 512;   // 2 blocks/CU x 256 CU: one generation
    DeformationCorrector_78967268704761_kernel<<<grid, 256, 0, stream>>>(
        F, W1, b1, W2, b2, W3, b3, out, N);
}

// Round 13
// 135.678 us; speedup vs baseline: 1.1994x; 1.1994x over previous
//
#include <hip/hip_runtime.h>

typedef _Float16 f16x8 __attribute__((ext_vector_type(8)));
typedef _Float16 f16x2 __attribute__((ext_vector_type(2)));
typedef __fp16   fp16x2r __attribute__((ext_vector_type(2)));   // cvt_pkrtz return type
typedef float    f32x4 __attribute__((ext_vector_type(4)));

#define MFMA(a, b, c) __builtin_amdgcn_mfma_f32_16x16x32_f16((a), (b), (c), 0, 0, 0)

__device__ inline f16x8 zero8() {
    f16x8 z;
#pragma unroll
    for (int i = 0; i < 8; ++i) z[i] = (_Float16)0.0f;
    return z;
}

// R10 base (81us, VGPR 124) + layer-3-only paired staging:
//   layer-3 staging col space c'' = 2*l15 + h (both pair operands already live
//   in AGPRs -> zero extra liveness), one cvt_pkrtz + one b32 store per pair.
//   W3c uses the R11-verified paired perm: ch = s*32 + (j&1)*16 + q*4 + (j>>1).
//   Layer-1 staging + W2f stay R10-canonical (R11 showed pairing layer-1 costs
//   +12 VGPR -> occupancy cliff).
// Occupancy law (R5-R11): arch VGPR + 128 acc <= 256 <=> 8 waves/CU. Keep
// arch VGPR <= 128. BAN: __launch_bounds__ min-waves >= 2 (5/5 miscompiles).
// Fragment maps: R3-hardware-verified canonical (A k=(lane>>4)*8+j;
// B k=(lane>>4)*8+j, n=lane&15; D m=(lane>>4)*4+r, n=lane&15).
__global__ __launch_bounds__(256, 1)
void DeformationCorrector_78967268704761_kernel(
        const float* __restrict__ F,
        const float* __restrict__ W1, const float* __restrict__ b1,
        const float* __restrict__ W2, const float* __restrict__ b2,
        const float* __restrict__ W3, const float* __restrict__ b3,
        float* __restrict__ out, int N)
{
    __shared__ __align__(16) _Float16 W2f[8][4][64][8];   // 32 KB canonical b-frags (verified R3)
    __shared__ __align__(16) _Float16 W1f[8][16][8];      // 2 KB  layer1 B-frags, lanes<16 (k<8)
    __shared__ __align__(16) _Float16 W3c[4][16][8];      // 1 KB  layer3 B-frags (paired-col perm, verified R11)
    __shared__ __align__(16) _Float16 invL[256][8];       // 4 KB  per-point invariants
    __shared__ __align__(16) _Float16 scratch[4][64][40]; // 20 KB per-wave h slice (also xls alias)

    const int tid  = threadIdx.x;
    const int lane = tid & 63;
    const int w    = tid >> 6;
    const int l15  = tid & 15;
    const int quad = (tid >> 4) & 3;

    // ---------------- weight pre-pack (once per block) ----------------
    for (int m = tid; m < 128 * 128; m += 256) {          // W2[k][n] -> canonical frag (R3-verified)
        int k = m >> 7, n = m & 127;
        W2f[n >> 4][k >> 5][((k >> 3) & 3) * 16 + (n & 15)][k & 7] = (_Float16)W2[m];
    }
    for (int f = tid; f < 1024; f += 256) {               // W1 b-frags: B[k=j][n], k=7 -> b1
        int nt = f >> 7, n15 = (f >> 3) & 15, j = f & 7;
        W1f[nt][n15][j] = (_Float16)((j < 7) ? W1[j * 128 + nt * 16 + n15]
                                             : b1[nt * 16 + n15]);
    }
    for (int f = tid; f < 512; f += 256) {                // W3 b-frags (paired-col perm, R11-verified)
        int s = f >> 7, idx = (f >> 3) & 15, j = f & 7;
        int q = idx >> 2, n3 = idx & 3;
        int ch = s * 32 + (j & 1) * 16 + q * 4 + (j >> 1);
        W3c[s][idx][j] = (_Float16)W3[ch * 4 + n3];
    }
    float b2r[8];
#pragma unroll
    for (int nt = 0; nt < 8; ++nt) b2r[nt] = b2[nt * 16 + l15];
    const float b3v = (l15 < 4) ? b3[l15] : 0.f;
    __syncthreads();   // only barrier; all main-loop LDS traffic is wave-private

    const int ntiles = (N + 255) >> 8;
    const int stride = (int)gridDim.x;

    // prime the F prefetch for the first tile
    float a, b, c, d;
    {
        const int p0 = blockIdx.x * 256 + tid;
        if (blockIdx.x < ntiles && p0 < N) {
            const float4 f4 = *(const float4*)(F + 4ll * p0);
            a = f4.x; b = f4.y; c = f4.z; d = f4.w;
        } else { a = 1.f; b = 0.f; c = 0.f; d = 1.f; }
    }

    for (int tile = blockIdx.x; tile < ntiles; tile += stride) {
        // ---------------- prefetch next tile's F (overlaps whole body) ----------------
        float na = 1.f, nb = 0.f, nc = 0.f, nd = 1.f;
        {
            const int pn = (tile + stride) * 256 + tid;
            if (tile + stride < ntiles && pn < N) {
                const float4 f4 = *(const float4*)(F + 4ll * pn);
                na = f4.x; nb = f4.y; nc = f4.z; nd = f4.w;
            }
        }
        const int p = tile * 256 + tid;

        // ---------------- invariants + polar (fp32, verified) ----------------
        const float x1 = a + d, y1 = c - b, x2 = a - d, y2 = c + b;
        const float h1v = sqrtf(x1 * x1 + y1 * y1);
        const float h2v = sqrtf(x2 * x2 + y2 * y2);
        const float s1 = 0.5f * (h1v + h2v), s2 = 0.5f * (h1v - h2v);
        const float ir = 1.0f / h1v;
        const float Rc = x1 * ir, Rs = y1 * ir;
        f16x8 iv;
        iv[0] = (_Float16)(s1 - 1.f);
        iv[1] = (_Float16)(s2 - 1.f);
        iv[2] = (_Float16)(a * a + c * c - 1.f);
        const float i3 = a * b + c * d;
        iv[3] = (_Float16)i3;
        iv[4] = (_Float16)i3;
        iv[5] = (_Float16)(b * b + d * d - 1.f);
        iv[6] = (_Float16)(a * d - b * c - 1.f);
        iv[7] = (_Float16)1.0f;
        *(f16x8*)(&invL[tid][0]) = iv;

        // inv A-frags: A[m=l15][k=quad*8+j], nonzero only quad==0 (k<8)
        f16x8 binv[4];
#pragma unroll
        for (int mt = 0; mt < 4; ++mt)
            binv[mt] = (quad == 0) ? *(const f16x8*)(&invL[w * 64 + mt * 16 + l15][0])
                                   : zero8();

        // ---------------- layers 1+2 per 32-channel chunk ----------------
        f32x4 acc2[8][4];   // [nt2][mt2]
#pragma unroll
        for (int nt2 = 0; nt2 < 8; ++nt2)
#pragma unroll
            for (int mt2 = 0; mt2 < 4; ++mt2) acc2[nt2][mt2] = (f32x4){0.f, 0.f, 0.f, 0.f};

        for (int ks = 0; ks < 4; ++ks) {
            // layer-1 MFMA: h1[pt][ch] for ch in [ks*32, ks*32+32) (R10 form)
#pragma unroll
            for (int h = 0; h < 2; ++h) {
                const f16x8 bw1 = (lane < 16) ? *(const f16x8*)(&W1f[2 * ks + h][l15][0])
                                              : zero8();
#pragma unroll
                for (int mt = 0; mt < 4; ++mt) {
                    f32x4 cz = {0.f, 0.f, 0.f, 0.f};
                    const f32x4 cc = MFMA(binv[mt], bw1, cz);
                    // D[pt = mt*16+quad*4+r][ch_local = h*16+l15] -> relu -> scratch
#pragma unroll
                    for (int r = 0; r < 4; ++r)
                        scratch[w][mt * 16 + quad * 4 + r][h * 16 + l15] =
                            (_Float16)fmaxf(cc[r], 0.f);
                }
            }
            // layer-2: canonical a-frags from slice + canonical W2 b-frags
            f16x8 af[4];
#pragma unroll
            for (int mt2 = 0; mt2 < 4; ++mt2)
                af[mt2] = *(const f16x8*)(&scratch[w][mt2 * 16 + l15][quad * 8]);
#pragma unroll
            for (int nt2 = 0; nt2 < 8; ++nt2) {
                const f16x8 bf = *(const f16x8*)(&W2f[nt2][ks][lane][0]);
#pragma unroll
                for (int mt2 = 0; mt2 < 4; ++mt2)
                    acc2[nt2][mt2] = MFMA(af[mt2], bf, acc2[nt2][mt2]);
            }
        }

        // ---------------- layer 3 per 32-channel chunk (paired staging) ----------------
        f32x4 acc3[4];
#pragma unroll
        for (int mt2 = 0; mt2 < 4; ++mt2) acc3[mt2] = (f32x4){0.f, 0.f, 0.f, 0.f};

#pragma unroll
        for (int s = 0; s < 4; ++s) {
            const float bb0 = b2r[2 * s], bb1 = b2r[2 * s + 1];
#pragma unroll
            for (int mt2 = 0; mt2 < 4; ++mt2)
#pragma unroll
                for (int r = 0; r < 4; ++r) {
                    // both pair operands already live in acc2 -> zero extra liveness
                    const fp16x2r pwr = __builtin_amdgcn_cvt_pkrtz(
                        fmaxf(acc2[2 * s + 0][mt2][r] + bb0, 0.f),
                        fmaxf(acc2[2 * s + 1][mt2][r] + bb1, 0.f));
                    *(f16x2*)(&scratch[w][mt2 * 16 + quad * 4 + r][2 * l15]) =
                        __builtin_bit_cast(f16x2, pwr);
                }
            const f16x8 bw3 = (l15 < 4) ? *(const f16x8*)(&W3c[s][quad * 4 + l15][0])
                                        : zero8();
#pragma unroll
            for (int mt2 = 0; mt2 < 4; ++mt2) {
                const f16x8 ah = *(const f16x8*)(&scratch[w][mt2 * 16 + l15][quad * 8]);
                acc3[mt2] = MFMA(ah, bw3, acc3[mt2]);
            }
        }

        // ---------------- epilogue: x via scratch alias -> R@x + F ----------------
        float* xf = (float*)(&scratch[w][0][0]);   // 1 KB of the 5 KB wave slice
#pragma unroll
        for (int mt2 = 0; mt2 < 4; ++mt2)
#pragma unroll
            for (int r = 0; r < 4; ++r)
                if (l15 < 4)
                    xf[(mt2 * 16 + quad * 4 + r) * 4 + l15] = acc3[mt2][r] + b3v;

        const float4 xv = *(const float4*)(&xf[lane * 4]);
        const float xm  = 0.5f * (xv.y + xv.z);
        const float d00 = Rc * xv.x - Rs * xm;
        const float d01 = Rc * xm   - Rs * xv.w;
        const float d10 = Rs * xv.x + Rc * xm;
        const float d11 = Rs * xm   + Rc * xv.w;
        if (p < N) {
            float4 o;
            o.x = a + d00; o.y = b + d01; o.z = c + d10; o.w = d + d11;
            *(float4*)(out + 4ll * p) = o;
        }

        // rotate prefetched F into place for the next tile
        a = na; b = nb; c = nc; d = nd;
    }
}

extern "C" void kernel_launch(void* const* d_in, const int* in_sizes, int n_in,
                              void* d_out, int out_size, void* d_ws, size_t ws_size,
                              hipStream_t stream) {
    const float* F  = (const float*)d_in[0];
    const float* W1 = (const float*)d_in[1];
    const float* b1 = (const float*)d_in[2];
    const float* W2 = (const float*)d_in[3];
    const float* b2 = (const float*)d_in[4];
    const float* W3 = (const float*)d_in[5];
    const float* b3 = (const float*)d_in[6];
    float* out = (float*)d_out;
    const int N = in_sizes[0] / 4;
    const int ntiles = (N + 255) / 256;
    const int grid = ntiles < 512 ? ntiles : 512;   // 2 blocks/CU x 256 CU: one generation
    DeformationCorrector_78967268704761_kernel<<<grid, 256, 0, stream>>>(
        F, W1, b1, W2, b2, W3, b3, out, N);
}